// Round 8
// baseline (270.978 us; speedup 1.0000x reference)
//
#include <hip/hip_runtime.h>
#include <math.h>

// Problem constants (match the jax reference)
constexpr int B_  = 2;
constexpr int C_  = 64;
constexpr int HW_ = 64 * 128;      // 8192
constexpr int N_  = HW_;           // points per image (near == far == 8192)
constexpr int NX_ = 512;
constexpr int NY_ = 512;
constexpr int NYNX_ = NX_ * NY_;   // 262144
constexpr int SEG_  = 64;          // near-dim segments (partial top-3 per seg)
constexpr int SEGN_ = N_ / SEG_;   // 128 near candidates per segment (2 KB tile)
constexpr int FPT_  = 4;           // far points per thread in nn_part
constexpr int BN_   = B_ * N_;     // 16384

// ---------------------------------------------------------------------------
// Shared voxel binning (numpy f32 bitwise). -1 = contributes nothing.
// ---------------------------------------------------------------------------
__device__ __forceinline__ int voxel_of(float x, float y, float w) {
#pragma clang fp contract(off)
  if (w == 0.0f) return -1;
  float qx = (x - 0.0f) / 0.1f;
  float qy = (y - (-25.6f)) / 0.1f;
  int ix = (int)floorf(qx);
  int iy = (int)floorf(qy);
  if (ix < 0 || ix >= NX_ || iy < 0 || iy >= NY_) return -1;
  return iy * NX_ + ix;
}

// ---------------------------------------------------------------------------
// Fused prep: blocks [0,64) pack+count points; blocks [64,320) transpose
// fv (B,C,HW) -> fvT (B,HW,C). The two halves are independent.
// ---------------------------------------------------------------------------
__global__ __launch_bounds__(256) void prep_kernel(
    const float* __restrict__ fv,
    const float* __restrict__ pi, const int* __restrict__ pm,
    const float* __restrict__ pif, const int* __restrict__ pmf,
    float4* __restrict__ near4, float4* __restrict__ far4,
    float4* __restrict__ nearnn, float* __restrict__ cnt,
    float* __restrict__ fvT) {
#pragma clang fp contract(off)
  __shared__ float tile[64][65];
  if (blockIdx.x < 64) {
    // ---- pack + count ----
    int t = blockIdx.x * 256 + threadIdx.x;        // over B_*N_
    int k = t / N_, n = t % N_;
    const float* base  = pi  + (size_t)k * 4 * HW_;
    const float* basef = pif + (size_t)k * 4 * HW_;
    float x = base[n], y = base[HW_ + n], z = base[2 * HW_ + n];
    bool v = pm[k * HW_ + n] > 0;
    near4[t] = make_float4(x, y, z, v ? 1.0f : 0.0f);
    float sq = (x * x + y * y) + z * z;   // numpy 3-elem sum order
    nearnn[t] = v ? make_float4(x, y, z, sq)
                 : make_float4(0.0f, 0.0f, 0.0f, 1e10f);
    float fx = basef[n], fy = basef[HW_ + n], fz = basef[2 * HW_ + n];
    bool vf = pmf[k * HW_ + n] > 0;
    far4[t] = make_float4(fx, fy, fz, vf ? 1.0f : 0.0f);

    int vn = voxel_of(x, y, v ? 1.0f : 0.0f);
    if (vn >= 0) atomicAdd(&cnt[(size_t)k * NYNX_ + vn], 1.0f);
    int vfv = voxel_of(fx, fy, vf ? 1.0f : 0.0f);
    if (vfv >= 0) atomicAdd(&cnt[(size_t)k * NYNX_ + vfv], 1.0f);
  } else {
    // ---- transpose ----
    int bid = blockIdx.x - 64;          // 0..255
    int k = bid >> 7;                   // /128
    int n0 = (bid & 127) * 64;
    int tx = threadIdx.x & 63, ty = threadIdx.x >> 6;
    for (int c = ty; c < C_; c += 4)
      tile[c][tx] = fv[((size_t)(k * C_ + c)) * HW_ + n0 + tx];
    __syncthreads();
    for (int nn = ty; nn < 64; nn += 4)
      fvT[((size_t)(k * HW_ + n0 + nn)) * C_ + tx] = tile[tx][nn];
  }
}

// ---------------------------------------------------------------------------
// Stable top-3 insert, value path (min + 2x med3) + index path (3 cmp +
// 5 cndmask). Case-exhaustively identical to the verified merge3: candidate
// loses ties; displaced incumbents shift down with their indices.
// ---------------------------------------------------------------------------
__device__ __forceinline__ void merge3_fast(float tv, int idx,
                                            float& b0, float& b1, float& b2,
                                            int& i0, int& i1, int& i2) {
  bool c0 = tv < b0;
  bool c1 = tv < b1;
  bool c2 = tv < b2;
  float nb0 = fminf(b0, tv);
  float nb1 = __builtin_amdgcn_fmed3f(b0, b1, tv);
  float nb2 = __builtin_amdgcn_fmed3f(b1, b2, tv);
  int oi0 = i0, oi1 = i1;
  i0 = c0 ? idx : i0;
  i1 = c0 ? oi0 : (c1 ? idx : i1);
  i2 = c1 ? oi1 : (c2 ? idx : i2);
  b0 = nb0; b1 = nb1; b2 = nb2;
}

// Full cndmask variant (merge paths where op count doesn't matter).
__device__ __forceinline__ void merge3(float tv, int idx,
                                       float& b0, float& b1, float& b2,
                                       int& i0, int& i1, int& i2) {
  bool c0 = tv < b0;
  bool c1 = tv < b1;
  bool c2 = tv < b2;
  float ob0 = b0, ob1 = b1;
  int   oi0 = i0, oi1 = i1;
  b0 = c0 ? tv : b0;                    i0 = c0 ? idx : i0;
  b1 = c0 ? ob0 : (c1 ? tv : b1);       i1 = c0 ? oi0 : (c1 ? idx : i1);
  b2 = c1 ? ob1 : (c2 ? tv : b2);       i2 = c1 ? oi1 : (c2 ? idx : i2);
}

// ---------------------------------------------------------------------------
// Partial 3-NN: 4 far points per thread; 128-candidate LDS tile (broadcast
// reads, conflict-free) -> 1 ds_read_b128 feeds ~64 VALU. d2 replicates the
// reference f32 bitwise: (sf + sq_near) - fma(az,qz, fma(ay,qy, ax*qx)).
// Partials stored SEGMENT-MAJOR: pd[(s*3+slot)*BN + g] for coalesced merge.
// Grid (8,64,2) = 1024 blocks = 4 blocks/CU = 16 waves/CU.
// ---------------------------------------------------------------------------
__global__ __launch_bounds__(256, 4) void nn_part_kernel(
    const float4* __restrict__ nearnn, const float4* __restrict__ far4,
    float* __restrict__ pd, int* __restrict__ pidx) {
#pragma clang fp contract(off)
  __shared__ float4 tile[SEGN_];
  int t = threadIdx.x;
  int fb = blockIdx.x;           // 0..7   far block (1024 far points each)
  int s  = blockIdx.y;           // 0..SEG_-1
  int k  = blockIdx.z;           // batch

  if (t < SEGN_) tile[t] = nearnn[k * N_ + s * SEGN_ + t];
  __syncthreads();

  int m0 = fb * (256 * FPT_) + t;
  float sf[FPT_], ax[FPT_], ay[FPT_], az[FPT_];
  float bv[FPT_][3];
  int   bi[FPT_][3];
#pragma unroll
  for (int j = 0; j < FPT_; ++j) {
    float4 f = far4[k * N_ + m0 + j * 256];
    sf[j] = (f.x * f.x + f.y * f.y) + f.z * f.z;   // numpy 3-elem order
    ax[j] = 2.0f * f.x; ay[j] = 2.0f * f.y; az[j] = 2.0f * f.z;
    bv[j][0] = 1e30f; bv[j][1] = 1e30f; bv[j][2] = 1e30f;
    bi[j][0] = 0; bi[j][1] = 0; bi[j][2] = 0;
  }

  int base_idx = s * SEGN_;
#pragma unroll 2
  for (int i = 0; i < SEGN_; ++i) {
    float4 q = tile[i];
    int idx = base_idx + i;
#pragma unroll
    for (int j = 0; j < FPT_; ++j) {
      float p0 = ax[j] * q.x;                               // round(ax*qx)
      float mm = __builtin_fmaf(az[j], q.z, __builtin_fmaf(ay[j], q.y, p0));
      float tv = (sf[j] + q.w) - mm;                        // masked -> ~1e10
      merge3_fast(tv, idx, bv[j][0], bv[j][1], bv[j][2],
                  bi[j][0], bi[j][1], bi[j][2]);
    }
  }

  int jb = s * 3;
#pragma unroll
  for (int j = 0; j < FPT_; ++j) {
    int g = k * N_ + m0 + j * 256;
    pd[(size_t)(jb + 0) * BN_ + g] = bv[j][0];
    pd[(size_t)(jb + 1) * BN_ + g] = bv[j][1];
    pd[(size_t)(jb + 2) * BN_ + g] = bv[j][2];
    pidx[(size_t)(jb + 0) * BN_ + g] = bi[j][0];
    pidx[(size_t)(jb + 1) * BN_ + g] = bi[j][1];
    pidx[(size_t)(jb + 2) * BN_ + g] = bi[j][2];
  }
}

// ---------------------------------------------------------------------------
// Fused mid: blocks [0,256) merge the SEG_*3 partials per far point (4
// threads/far, contiguous ascending j-ranges preserve the lowest-index tie
// rule); blocks [256,2304) zero acc rows where cnt>=2. Independent halves.
// ---------------------------------------------------------------------------
__global__ __launch_bounds__(256) void mid_kernel(
    const float* __restrict__ pd, const int* __restrict__ pidx,
    int* __restrict__ nn_idx, float* __restrict__ nn_w,
    const float* __restrict__ cnt, float* __restrict__ acc) {
#pragma clang fp contract(off)
  constexpr int Q = 4;                   // threads per far point
  constexpr int J = SEG_ * 3 / Q;        // 48 candidates per thread
  __shared__ float md[Q][64][3];
  __shared__ int   mi[Q][64][3];
  if (blockIdx.x < 256) {
    int t = threadIdx.x;
    int q  = t >> 6;                       // 0..3
    int gl = t & 63;
    int g = blockIdx.x * 64 + gl;          // far point id (over BN_)

    float b0 = 1e30f, b1 = 1e30f, b2 = 1e30f;
    int i0 = 0, i1 = 0, i2 = 0;
    int j0 = q * J;
    for (int j = 0; j < J; ++j) {
      float d = pd[(size_t)(j0 + j) * BN_ + g];
      int   ix = pidx[(size_t)(j0 + j) * BN_ + g];
      merge3(d, ix, b0, b1, b2, i0, i1, i2);
    }
    md[q][gl][0] = b0; md[q][gl][1] = b1; md[q][gl][2] = b2;
    mi[q][gl][0] = i0; mi[q][gl][1] = i1; mi[q][gl][2] = i2;
    __syncthreads();

    if (q == 0) {
      float c0 = 1e30f, c1 = 1e30f, c2 = 1e30f;
      int k0 = 0, k1 = 0, k2 = 0;
      for (int qq = 0; qq < Q; ++qq)
        for (int j = 0; j < 3; ++j)
          merge3(md[qq][gl][j], mi[qq][gl][j], c0, c1, c2, k0, k1, k2);
      float r0 = 1.0f / (c0 + 1e-8f);
      float r1 = 1.0f / (c1 + 1e-8f);
      float r2 = 1.0f / (c2 + 1e-8f);
      float rs = (r0 + r1) + r2;
      int o = g * 3;
      nn_idx[o] = k0; nn_idx[o + 1] = k1; nn_idx[o + 2] = k2;
      nn_w[o] = r0 / rs; nn_w[o + 1] = r1 / rs; nn_w[o + 2] = r2 / rs;
    }
  } else {
    // ---- zero collision rows (~130/batch) ----
    int t = (blockIdx.x - 256) * 256 + threadIdx.x;  // over B_*NYNX_
    if (cnt[t] >= 2.0f) {
      float4* row = (float4*)(acc + (size_t)t * C_);
      float4 z = make_float4(0.0f, 0.0f, 0.0f, 0.0f);
      for (int i = 0; i < C_ / 4; ++i) row[i] = z;
    }
  }
}

// ---------------------------------------------------------------------------
// Scatter features into voxel-major acc (k,v,C). Wave per point, lane =
// channel. cnt==1 (98%): plain coalesced store. cnt>=2: row atomics.
// ---------------------------------------------------------------------------
__global__ __launch_bounds__(256) void scatter_feat_kernel(
    const float4* __restrict__ near4, const float4* __restrict__ far4,
    const float* __restrict__ fvT,
    const int* __restrict__ nn_idx, const float* __restrict__ nn_w,
    const float* __restrict__ cnt, float* __restrict__ acc) {
#pragma clang fp contract(off)
  int lane = threadIdx.x & 63;
  int wv = blockIdx.x * 4 + (threadIdx.x >> 6);  // global wave id = point slot
  int k = wv / (2 * N_);
  int p = wv % (2 * N_);
  bool is_far = p >= N_;
  int n = is_far ? p - N_ : p;

  float4 pt = is_far ? far4[k * N_ + n] : near4[k * N_ + n];
  int v = voxel_of(pt.x, pt.y, pt.w);
  if (v < 0) return;

  float val;
  if (!is_far) {
    val = fvT[((size_t)(k * N_ + n)) * C_ + lane];
  } else {
    int o = (k * N_ + n) * 3;
    int i0 = nn_idx[o], i1 = nn_idx[o + 1], i2 = nn_idx[o + 2];
    float w0 = nn_w[o], w1 = nn_w[o + 1], w2 = nn_w[o + 2];
    val = w0 * fvT[((size_t)(k * N_ + i0)) * C_ + lane]
        + w1 * fvT[((size_t)(k * N_ + i1)) * C_ + lane]
        + w2 * fvT[((size_t)(k * N_ + i2)) * C_ + lane];
  }
  size_t rowoff = ((size_t)k * NYNX_ + v) * C_;
  float cn = cnt[(size_t)k * NYNX_ + v];   // wave-uniform
  if (cn == 1.0f) acc[rowoff + lane] = val;
  else            atomicAdd(&acc[rowoff + lane], val);
}

// ---------------------------------------------------------------------------
// Emit out (B,C,NY,NX) from acc/cnt via LDS transpose. Per block: 64 voxels.
// Phase 1: coalesced float4 row-gathers of occupied rows (divide fused),
// zeros otherwise. Phase 2: coalesced float4 out stores. Covers every out
// element exactly once (fuses the zero-fill).
// ---------------------------------------------------------------------------
__global__ __launch_bounds__(256) void emit_kernel(
    const float* __restrict__ acc, const float* __restrict__ cnt,
    float* __restrict__ out) {
#pragma clang fp contract(off)
  __shared__ float tile[64][65];
  __shared__ float cs[64];
  int t = threadIdx.x;
  int k = blockIdx.y;
  int v0 = blockIdx.x * 64;

  if (t < 64) cs[t] = cnt[(size_t)k * NYNX_ + v0 + t];
  __syncthreads();

  const float4* acc4 = (const float4*)acc;
#pragma unroll
  for (int p = 0; p < 4; ++p) {
    int row = p * 16 + (t >> 4);     // voxel within block
    int f4  = t & 15;                // float4 within the 64-channel row
    float c = cs[row];
    float4 a = make_float4(0.0f, 0.0f, 0.0f, 0.0f);
    if (c > 0.0f) {
      a = acc4[((size_t)k * NYNX_ + v0 + row) * (C_ / 4) + f4];
      a.x /= c; a.y /= c; a.z /= c; a.w /= c;
    }
    tile[f4 * 4 + 0][row] = a.x;
    tile[f4 * 4 + 1][row] = a.y;
    tile[f4 * 4 + 2][row] = a.z;
    tile[f4 * 4 + 3][row] = a.w;
  }
  __syncthreads();

#pragma unroll
  for (int p = 0; p < 4; ++p) {
    int c  = p * 16 + (t >> 4);      // channel
    int xq = t & 15;                 // float4 of voxels
    float4 o = make_float4(tile[c][xq * 4 + 0], tile[c][xq * 4 + 1],
                           tile[c][xq * 4 + 2], tile[c][xq * 4 + 3]);
    ((float4*)out)[(((size_t)k * C_ + c) * NYNX_ + v0) / 4 + xq] = o;
  }
}

extern "C" void kernel_launch(void* const* d_in, const int* in_sizes, int n_in,
                              void* d_out, int out_size, void* d_ws, size_t ws_size,
                              hipStream_t stream) {
  const float* fv  = (const float*)d_in[0];  // (B,C,H,W)
  const float* pi  = (const float*)d_in[1];  // (B,4,H,W)
  const int*   pm  = (const int*)d_in[2];    // (B,H,W)
  const float* pif = (const float*)d_in[3];  // (B,4,H,W)
  const int*   pmf = (const int*)d_in[4];    // (B,H,W)
  float* out = (float*)d_out;                // (B,C,NY,NX) f32

  // workspace layout (16B aligned): small buffers ~7.5 MB, acc 134 MB at +8MB.
  char* wsb = (char*)d_ws;
  float*  fvT    = (float*)(wsb);                 // B*HW*C*4      = 4,194,304
  float*  cnt    = (float*)(wsb + 4194304);       // B*NYNX*4      = 2,097,152
  float4* near4  = (float4*)(wsb + 6291456);      // B*N*16        =   262,144
  float4* far4   = (float4*)(wsb + 6553600);      // B*N*16        =   262,144
  float4* nearnn = (float4*)(wsb + 6815744);      // B*N*16        =   262,144
  int*    nnidx  = (int*)(wsb + 7077888);         // B*N*3*4       =   196,608
  float*  nnw    = (float*)(wsb + 7274496);       // B*N*3*4       =   196,608
  float*  acc    = (float*)(wsb + 8388608);       // B*NYNX*C*4    = 134,217,728

  // Partial top-3 buffers live in d_out's head (consumed by mid_kernel before
  // emit overwrites out): pd 12.6 MB + pidx 12.6 MB (segment-major).
  float* pd   = out;
  int*   pidx = (int*)(out + (size_t)SEG_ * 3 * BN_);

  hipMemsetAsync(cnt, 0, (size_t)B_ * NYNX_ * sizeof(float), stream);

  prep_kernel<<<320, 256, 0, stream>>>(
      fv, pi, pm, pif, pmf, near4, far4, nearnn, cnt, fvT);
  nn_part_kernel<<<dim3(N_ / (256 * FPT_), SEG_, B_), 256, 0, stream>>>(
      nearnn, far4, pd, pidx);
  mid_kernel<<<256 + B_ * NYNX_ / 256, 256, 0, stream>>>(
      pd, pidx, nnidx, nnw, cnt, acc);
  scatter_feat_kernel<<<B_ * 2 * N_ / 4, 256, 0, stream>>>(
      near4, far4, fvT, nnidx, nnw, cnt, acc);
  emit_kernel<<<dim3(NYNX_ / 64, B_), 256, 0, stream>>>(acc, cnt, out);
}

// Round 9
// 237.440 us; speedup vs baseline: 1.1412x; 1.1412x over previous
//
#include <hip/hip_runtime.h>
#include <math.h>

// Problem constants (match the jax reference)
constexpr int B_  = 2;
constexpr int C_  = 64;
constexpr int HW_ = 64 * 128;      // 8192
constexpr int N_  = HW_;           // points per image (near == far == 8192)
constexpr int NX_ = 512;
constexpr int NY_ = 512;
constexpr int NYNX_ = NX_ * NY_;   // 262144
constexpr int SEG_  = 64;          // near-dim segments (partial top-3 per seg)
constexpr int SEGN_ = N_ / SEG_;   // 128 near candidates per segment (2 KB tile)
constexpr int FPT_  = 2;           // far points per thread in nn_part
                                   // (R8 post-mortem: FPT=4 @4 blocks/CU regressed
                                   //  102us vs ~65us; 8 blocks/CU is the lever)
constexpr int BN_   = B_ * N_;     // 16384

// ---------------------------------------------------------------------------
// Shared voxel binning (numpy f32 bitwise). -1 = contributes nothing.
// ---------------------------------------------------------------------------
__device__ __forceinline__ int voxel_of(float x, float y, float w) {
#pragma clang fp contract(off)
  if (w == 0.0f) return -1;
  float qx = (x - 0.0f) / 0.1f;
  float qy = (y - (-25.6f)) / 0.1f;
  int ix = (int)floorf(qx);
  int iy = (int)floorf(qy);
  if (ix < 0 || ix >= NX_ || iy < 0 || iy >= NY_) return -1;
  return iy * NX_ + ix;
}

// ---------------------------------------------------------------------------
// Fused prep: blocks [0,64) pack+count points; blocks [64,320) transpose
// fv (B,C,HW) -> fvT (B,HW,C). The two halves are independent.
// ---------------------------------------------------------------------------
__global__ __launch_bounds__(256) void prep_kernel(
    const float* __restrict__ fv,
    const float* __restrict__ pi, const int* __restrict__ pm,
    const float* __restrict__ pif, const int* __restrict__ pmf,
    float4* __restrict__ near4, float4* __restrict__ far4,
    float4* __restrict__ nearnn, float* __restrict__ cnt,
    float* __restrict__ fvT) {
#pragma clang fp contract(off)
  __shared__ float tile[64][65];
  if (blockIdx.x < 64) {
    // ---- pack + count ----
    int t = blockIdx.x * 256 + threadIdx.x;        // over B_*N_
    int k = t / N_, n = t % N_;
    const float* base  = pi  + (size_t)k * 4 * HW_;
    const float* basef = pif + (size_t)k * 4 * HW_;
    float x = base[n], y = base[HW_ + n], z = base[2 * HW_ + n];
    bool v = pm[k * HW_ + n] > 0;
    near4[t] = make_float4(x, y, z, v ? 1.0f : 0.0f);
    float sq = (x * x + y * y) + z * z;   // numpy 3-elem sum order
    nearnn[t] = v ? make_float4(x, y, z, sq)
                 : make_float4(0.0f, 0.0f, 0.0f, 1e10f);
    float fx = basef[n], fy = basef[HW_ + n], fz = basef[2 * HW_ + n];
    bool vf = pmf[k * HW_ + n] > 0;
    far4[t] = make_float4(fx, fy, fz, vf ? 1.0f : 0.0f);

    int vn = voxel_of(x, y, v ? 1.0f : 0.0f);
    if (vn >= 0) atomicAdd(&cnt[(size_t)k * NYNX_ + vn], 1.0f);
    int vfv = voxel_of(fx, fy, vf ? 1.0f : 0.0f);
    if (vfv >= 0) atomicAdd(&cnt[(size_t)k * NYNX_ + vfv], 1.0f);
  } else {
    // ---- transpose ----
    int bid = blockIdx.x - 64;          // 0..255
    int k = bid >> 7;                   // /128
    int n0 = (bid & 127) * 64;
    int tx = threadIdx.x & 63, ty = threadIdx.x >> 6;
    for (int c = ty; c < C_; c += 4)
      tile[c][tx] = fv[((size_t)(k * C_ + c)) * HW_ + n0 + tx];
    __syncthreads();
    for (int nn = ty; nn < 64; nn += 4)
      fvT[((size_t)(k * HW_ + n0 + nn)) * C_ + tx] = tile[tx][nn];
  }
}

// ---------------------------------------------------------------------------
// Stable top-3 insert, value path (min + 2x med3) + index path (3 cmp +
// 5 cndmask). Case-exhaustively identical to the verified merge3: candidate
// loses ties; displaced incumbents shift down with their indices.
// ---------------------------------------------------------------------------
__device__ __forceinline__ void merge3_fast(float tv, int idx,
                                            float& b0, float& b1, float& b2,
                                            int& i0, int& i1, int& i2) {
  bool c0 = tv < b0;
  bool c1 = tv < b1;
  bool c2 = tv < b2;
  float nb0 = fminf(b0, tv);
  float nb1 = __builtin_amdgcn_fmed3f(b0, b1, tv);
  float nb2 = __builtin_amdgcn_fmed3f(b1, b2, tv);
  int oi0 = i0, oi1 = i1;
  i0 = c0 ? idx : i0;
  i1 = c0 ? oi0 : (c1 ? idx : i1);
  i2 = c1 ? oi1 : (c2 ? idx : i2);
  b0 = nb0; b1 = nb1; b2 = nb2;
}

// Full cndmask variant (merge paths where op count doesn't matter).
__device__ __forceinline__ void merge3(float tv, int idx,
                                       float& b0, float& b1, float& b2,
                                       int& i0, int& i1, int& i2) {
  bool c0 = tv < b0;
  bool c1 = tv < b1;
  bool c2 = tv < b2;
  float ob0 = b0, ob1 = b1;
  int   oi0 = i0, oi1 = i1;
  b0 = c0 ? tv : b0;                    i0 = c0 ? idx : i0;
  b1 = c0 ? ob0 : (c1 ? tv : b1);       i1 = c0 ? oi0 : (c1 ? idx : i1);
  b2 = c1 ? ob1 : (c2 ? tv : b2);       i2 = c1 ? oi1 : (c2 ? idx : i2);
}

// ---------------------------------------------------------------------------
// Partial 3-NN (R7 config — best measured): 2 far points per thread;
// 128-candidate LDS tile (broadcast reads, conflict-free). d2 replicates the
// reference f32 bitwise: (sf + sq_near) - fma(az,qz, fma(ay,qy, ax*qx)).
// Partials stored SEGMENT-MAJOR: pd[(s*3+slot)*BN + g] for coalesced merge.
// Grid (16,64,2) = 2048 blocks = 8 blocks/CU = 32 waves/CU.
// ---------------------------------------------------------------------------
__global__ __launch_bounds__(256, 8) void nn_part_kernel(
    const float4* __restrict__ nearnn, const float4* __restrict__ far4,
    float* __restrict__ pd, int* __restrict__ pidx) {
#pragma clang fp contract(off)
  __shared__ float4 tile[SEGN_];
  int t = threadIdx.x;
  int fb = blockIdx.x;           // 0..15  far block (512 far points each)
  int s  = blockIdx.y;           // 0..SEG_-1
  int k  = blockIdx.z;           // batch

  if (t < SEGN_) tile[t] = nearnn[k * N_ + s * SEGN_ + t];
  __syncthreads();

  int m0 = fb * (256 * FPT_) + t;
  int m1 = m0 + 256;
  float4 f0 = far4[k * N_ + m0];
  float4 f1 = far4[k * N_ + m1];
  float sf0 = (f0.x * f0.x + f0.y * f0.y) + f0.z * f0.z;  // numpy 3-elem order
  float sf1 = (f1.x * f1.x + f1.y * f1.y) + f1.z * f1.z;
  float ax0 = 2.0f * f0.x, ay0 = 2.0f * f0.y, az0 = 2.0f * f0.z;
  float ax1 = 2.0f * f1.x, ay1 = 2.0f * f1.y, az1 = 2.0f * f1.z;

  float a0 = 1e30f, a1 = 1e30f, a2 = 1e30f;
  float b0 = 1e30f, b1 = 1e30f, b2 = 1e30f;
  int ia0 = 0, ia1 = 0, ia2 = 0;
  int ib0 = 0, ib1 = 0, ib2 = 0;
  int base_idx = s * SEGN_;
#pragma unroll 4
  for (int i = 0; i < SEGN_; ++i) {
    float4 q = tile[i];
    int idx = base_idx + i;
    float p0 = ax0 * q.x;                                  // round(ax*qx)
    float mm0 = __builtin_fmaf(az0, q.z, __builtin_fmaf(ay0, q.y, p0));
    float tv0 = (sf0 + q.w) - mm0;                         // masked -> ~1e10
    merge3_fast(tv0, idx, a0, a1, a2, ia0, ia1, ia2);
    float p1 = ax1 * q.x;
    float mm1 = __builtin_fmaf(az1, q.z, __builtin_fmaf(ay1, q.y, p1));
    float tv1 = (sf1 + q.w) - mm1;
    merge3_fast(tv1, idx, b0, b1, b2, ib0, ib1, ib2);
  }

  int g0 = k * N_ + m0, g1 = k * N_ + m1;
  int jb = s * 3;
  pd[(size_t)(jb + 0) * BN_ + g0] = a0;
  pd[(size_t)(jb + 1) * BN_ + g0] = a1;
  pd[(size_t)(jb + 2) * BN_ + g0] = a2;
  pidx[(size_t)(jb + 0) * BN_ + g0] = ia0;
  pidx[(size_t)(jb + 1) * BN_ + g0] = ia1;
  pidx[(size_t)(jb + 2) * BN_ + g0] = ia2;
  pd[(size_t)(jb + 0) * BN_ + g1] = b0;
  pd[(size_t)(jb + 1) * BN_ + g1] = b1;
  pd[(size_t)(jb + 2) * BN_ + g1] = b2;
  pidx[(size_t)(jb + 0) * BN_ + g1] = ib0;
  pidx[(size_t)(jb + 1) * BN_ + g1] = ib1;
  pidx[(size_t)(jb + 2) * BN_ + g1] = ib2;
}

// ---------------------------------------------------------------------------
// Fused mid: blocks [0,256) merge the SEG_*3 partials per far point (4
// threads/far, contiguous ascending j-ranges preserve the lowest-index tie
// rule); blocks [256,2304) zero acc rows where cnt>=2. Independent halves.
// ---------------------------------------------------------------------------
__global__ __launch_bounds__(256) void mid_kernel(
    const float* __restrict__ pd, const int* __restrict__ pidx,
    int* __restrict__ nn_idx, float* __restrict__ nn_w,
    const float* __restrict__ cnt, float* __restrict__ acc) {
#pragma clang fp contract(off)
  constexpr int Q = 4;                   // threads per far point
  constexpr int J = SEG_ * 3 / Q;        // 48 candidates per thread
  __shared__ float md[Q][64][3];
  __shared__ int   mi[Q][64][3];
  if (blockIdx.x < 256) {
    int t = threadIdx.x;
    int q  = t >> 6;                       // 0..3
    int gl = t & 63;
    int g = blockIdx.x * 64 + gl;          // far point id (over BN_)

    float b0 = 1e30f, b1 = 1e30f, b2 = 1e30f;
    int i0 = 0, i1 = 0, i2 = 0;
    int j0 = q * J;
    for (int j = 0; j < J; ++j) {
      float d = pd[(size_t)(j0 + j) * BN_ + g];
      int   ix = pidx[(size_t)(j0 + j) * BN_ + g];
      merge3(d, ix, b0, b1, b2, i0, i1, i2);
    }
    md[q][gl][0] = b0; md[q][gl][1] = b1; md[q][gl][2] = b2;
    mi[q][gl][0] = i0; mi[q][gl][1] = i1; mi[q][gl][2] = i2;
    __syncthreads();

    if (q == 0) {
      float c0 = 1e30f, c1 = 1e30f, c2 = 1e30f;
      int k0 = 0, k1 = 0, k2 = 0;
      for (int qq = 0; qq < Q; ++qq)
        for (int j = 0; j < 3; ++j)
          merge3(md[qq][gl][j], mi[qq][gl][j], c0, c1, c2, k0, k1, k2);
      float r0 = 1.0f / (c0 + 1e-8f);
      float r1 = 1.0f / (c1 + 1e-8f);
      float r2 = 1.0f / (c2 + 1e-8f);
      float rs = (r0 + r1) + r2;
      int o = g * 3;
      nn_idx[o] = k0; nn_idx[o + 1] = k1; nn_idx[o + 2] = k2;
      nn_w[o] = r0 / rs; nn_w[o + 1] = r1 / rs; nn_w[o + 2] = r2 / rs;
    }
  } else {
    // ---- zero collision rows (~130/batch) ----
    int t = (blockIdx.x - 256) * 256 + threadIdx.x;  // over B_*NYNX_
    if (cnt[t] >= 2.0f) {
      float4* row = (float4*)(acc + (size_t)t * C_);
      float4 z = make_float4(0.0f, 0.0f, 0.0f, 0.0f);
      for (int i = 0; i < C_ / 4; ++i) row[i] = z;
    }
  }
}

// ---------------------------------------------------------------------------
// Scatter features into voxel-major acc (k,v,C). Wave per point, lane =
// channel. cnt==1 (98%): plain coalesced store. cnt>=2: row atomics.
// ---------------------------------------------------------------------------
__global__ __launch_bounds__(256) void scatter_feat_kernel(
    const float4* __restrict__ near4, const float4* __restrict__ far4,
    const float* __restrict__ fvT,
    const int* __restrict__ nn_idx, const float* __restrict__ nn_w,
    const float* __restrict__ cnt, float* __restrict__ acc) {
#pragma clang fp contract(off)
  int lane = threadIdx.x & 63;
  int wv = blockIdx.x * 4 + (threadIdx.x >> 6);  // global wave id = point slot
  int k = wv / (2 * N_);
  int p = wv % (2 * N_);
  bool is_far = p >= N_;
  int n = is_far ? p - N_ : p;

  float4 pt = is_far ? far4[k * N_ + n] : near4[k * N_ + n];
  int v = voxel_of(pt.x, pt.y, pt.w);
  if (v < 0) return;

  float val;
  if (!is_far) {
    val = fvT[((size_t)(k * N_ + n)) * C_ + lane];
  } else {
    int o = (k * N_ + n) * 3;
    int i0 = nn_idx[o], i1 = nn_idx[o + 1], i2 = nn_idx[o + 2];
    float w0 = nn_w[o], w1 = nn_w[o + 1], w2 = nn_w[o + 2];
    val = w0 * fvT[((size_t)(k * N_ + i0)) * C_ + lane]
        + w1 * fvT[((size_t)(k * N_ + i1)) * C_ + lane]
        + w2 * fvT[((size_t)(k * N_ + i2)) * C_ + lane];
  }
  size_t rowoff = ((size_t)k * NYNX_ + v) * C_;
  float cn = cnt[(size_t)k * NYNX_ + v];   // wave-uniform
  if (cn == 1.0f) acc[rowoff + lane] = val;
  else            atomicAdd(&acc[rowoff + lane], val);
}

// ---------------------------------------------------------------------------
// Emit out (B,C,NY,NX) from acc/cnt via LDS transpose. Per block: 64 voxels.
// Phase 1: coalesced float4 row-gathers of occupied rows (divide fused),
// zeros otherwise. Phase 2: coalesced float4 out stores. Covers every out
// element exactly once (fuses the zero-fill).
// ---------------------------------------------------------------------------
__global__ __launch_bounds__(256) void emit_kernel(
    const float* __restrict__ acc, const float* __restrict__ cnt,
    float* __restrict__ out) {
#pragma clang fp contract(off)
  __shared__ float tile[64][65];
  __shared__ float cs[64];
  int t = threadIdx.x;
  int k = blockIdx.y;
  int v0 = blockIdx.x * 64;

  if (t < 64) cs[t] = cnt[(size_t)k * NYNX_ + v0 + t];
  __syncthreads();

  const float4* acc4 = (const float4*)acc;
#pragma unroll
  for (int p = 0; p < 4; ++p) {
    int row = p * 16 + (t >> 4);     // voxel within block
    int f4  = t & 15;                // float4 within the 64-channel row
    float c = cs[row];
    float4 a = make_float4(0.0f, 0.0f, 0.0f, 0.0f);
    if (c > 0.0f) {
      a = acc4[((size_t)k * NYNX_ + v0 + row) * (C_ / 4) + f4];
      a.x /= c; a.y /= c; a.z /= c; a.w /= c;
    }
    tile[f4 * 4 + 0][row] = a.x;
    tile[f4 * 4 + 1][row] = a.y;
    tile[f4 * 4 + 2][row] = a.z;
    tile[f4 * 4 + 3][row] = a.w;
  }
  __syncthreads();

#pragma unroll
  for (int p = 0; p < 4; ++p) {
    int c  = p * 16 + (t >> 4);      // channel
    int xq = t & 15;                 // float4 of voxels
    float4 o = make_float4(tile[c][xq * 4 + 0], tile[c][xq * 4 + 1],
                           tile[c][xq * 4 + 2], tile[c][xq * 4 + 3]);
    ((float4*)out)[(((size_t)k * C_ + c) * NYNX_ + v0) / 4 + xq] = o;
  }
}

extern "C" void kernel_launch(void* const* d_in, const int* in_sizes, int n_in,
                              void* d_out, int out_size, void* d_ws, size_t ws_size,
                              hipStream_t stream) {
  const float* fv  = (const float*)d_in[0];  // (B,C,H,W)
  const float* pi  = (const float*)d_in[1];  // (B,4,H,W)
  const int*   pm  = (const int*)d_in[2];    // (B,H,W)
  const float* pif = (const float*)d_in[3];  // (B,4,H,W)
  const int*   pmf = (const int*)d_in[4];    // (B,H,W)
  float* out = (float*)d_out;                // (B,C,NY,NX) f32

  // workspace layout (16B aligned): small buffers ~7.5 MB, acc 134 MB at +8MB.
  char* wsb = (char*)d_ws;
  float*  fvT    = (float*)(wsb);                 // B*HW*C*4      = 4,194,304
  float*  cnt    = (float*)(wsb + 4194304);       // B*NYNX*4      = 2,097,152
  float4* near4  = (float4*)(wsb + 6291456);      // B*N*16        =   262,144
  float4* far4   = (float4*)(wsb + 6553600);      // B*N*16        =   262,144
  float4* nearnn = (float4*)(wsb + 6815744);      // B*N*16        =   262,144
  int*    nnidx  = (int*)(wsb + 7077888);         // B*N*3*4       =   196,608
  float*  nnw    = (float*)(wsb + 7274496);       // B*N*3*4       =   196,608
  float*  acc    = (float*)(wsb + 8388608);       // B*NYNX*C*4    = 134,217,728

  // Partial top-3 buffers live in d_out's head (consumed by mid_kernel before
  // emit overwrites out): pd 12.6 MB + pidx 12.6 MB (segment-major).
  float* pd   = out;
  int*   pidx = (int*)(out + (size_t)SEG_ * 3 * BN_);

  hipMemsetAsync(cnt, 0, (size_t)B_ * NYNX_ * sizeof(float), stream);

  prep_kernel<<<320, 256, 0, stream>>>(
      fv, pi, pm, pif, pmf, near4, far4, nearnn, cnt, fvT);
  nn_part_kernel<<<dim3(N_ / (256 * FPT_), SEG_, B_), 256, 0, stream>>>(
      nearnn, far4, pd, pidx);
  mid_kernel<<<256 + B_ * NYNX_ / 256, 256, 0, stream>>>(
      pd, pidx, nnidx, nnw, cnt, acc);
  scatter_feat_kernel<<<B_ * 2 * N_ / 4, 256, 0, stream>>>(
      near4, far4, fvT, nnidx, nnw, cnt, acc);
  emit_kernel<<<dim3(NYNX_ / 64, B_), 256, 0, stream>>>(acc, cnt, out);
}